// Round 3
// baseline (27.379 us; speedup 1.0000x reference)
//
#include <hip/hip_runtime.h>
#include <math.h>

#define BATCH 16
#define SEQ 1024
#define MHEADS 4
#define DIM 64
#define WAVES 16            // waves per block
#define CHUNK (SEQ / WAVES) // 64 positions per wave

__global__ __launch_bounds__(WAVES * 64)
void teedam_scan_kernel(const float* __restrict__ values,
                        const float* __restrict__ pre,
                        const float* __restrict__ mask,
                        float* __restrict__ out) {
    const int b    = blockIdx.x >> 2;   // 0..15
    const int m    = blockIdx.x & 3;    // 0..3
    const int tid  = threadIdx.x;
    const int w    = tid >> 6;          // wave id 0..15
    const int lane = tid & 63;          // dim index d

    __shared__ float lds_M[WAVES];
    __shared__ float lds_S[WAVES];
    __shared__ float lds_A[WAVES][DIM];

    const int c0 = w * CHUNK;           // chunk start position
    // per-lane preattention for position c0+lane (broadcast later via shfl)
    const float  pre_l = pre[((size_t)(b * SEQ + c0 + lane)) * MHEADS + m];
    const float* vptr  = values + ((size_t)(b * SEQ + c0)) * DIM + lane;

    // ---- pass 1: chunk-local online-softmax summary ----
    float M = -INFINITY, S = 0.f, A = 0.f;
    #pragma unroll 8
    for (int q = 0; q < CHUNK; ++q) {
        float pq  = __shfl(pre_l, q, 64);
        float v   = vptr[q * DIM];
        float nM  = fmaxf(M, pq);
        float sc  = __expf(M - nM);
        float wgt = __expf(pq - nM);
        S = S * sc + wgt;
        A = A * sc + wgt * v;
        M = nM;
    }
    if (lane == 0) { lds_M[w] = M; lds_S[w] = S; }
    lds_A[w][lane] = A;
    __syncthreads();

    // ---- pass 2: per-wave prefix combine over earlier chunks ----
    float Mp = -INFINITY, Sp = 0.f, Ap = 0.f;
    for (int j = 0; j < w; ++j) {
        float Mj = lds_M[j], Sj = lds_S[j], Aj = lds_A[j][lane];
        float nM = fmaxf(Mp, Mj);
        float e1 = __expf(Mp - nM);
        float e2 = __expf(Mj - nM);
        Sp = Sp * e1 + Sj * e2;
        Ap = Ap * e1 + Aj * e2;
        Mp = nM;
    }

    // ---- pass 3: rescan chunk from prefix, write outputs ----
    M = Mp; S = Sp; A = Ap;
    const float* maskp = mask + (size_t)b * SEQ + c0;
    float* optr = out + (((size_t)(b * SEQ + c0)) * MHEADS + m) * DIM + lane;
    #pragma unroll 4
    for (int q = 0; q < CHUNK; ++q) {
        float pq  = __shfl(pre_l, q, 64);
        float v   = vptr[q * DIM];
        float nM  = fmaxf(M, pq);
        float sc  = __expf(M - nM);
        float wgt = __expf(pq - nM);
        S = S * sc + wgt;
        A = A * sc + wgt * v;
        M = nM;
        float o = A * (maskp[q] / S);
        optr[(size_t)q * MHEADS * DIM] = o;
    }
}

extern "C" void kernel_launch(void* const* d_in, const int* in_sizes, int n_in,
                              void* d_out, int out_size, void* d_ws, size_t ws_size,
                              hipStream_t stream) {
    const float* values = (const float*)d_in[0];
    const float* pre    = (const float*)d_in[1];
    const float* mask   = (const float*)d_in[2];
    float*       out    = (float*)d_out;

    dim3 grid(BATCH * MHEADS);
    dim3 block(WAVES * 64);
    hipLaunchKernelGGL(teedam_scan_kernel, grid, block, 0, stream,
                       values, pre, mask, out);
}

// Round 9
// 18.117 us; speedup vs baseline: 1.5112x; 1.5112x over previous
//
#include <hip/hip_runtime.h>
#include <math.h>

#define BATCH 16
#define SEQ 1024
#define MH 4
#define DIM 64
#define NCHUNK 8
#define CHUNK 128           // positions per block
#define WAVES 8
#define WSEG 16             // positions per wave in local scan
#define THREADS (WAVES * 64)

// One block per (b, m, chunk-of-128). Lane d owns dim d. Unnormalized-exp
// cumsum (stable via per-chain max G); prefix over earlier chunks computed
// redundantly in-block (values are L2/L3-resident: 4 MB total).
__global__ __launch_bounds__(THREADS)
void teedam_kernel(const float* __restrict__ values,
                   const float* __restrict__ pre,
                   const float* __restrict__ mask,
                   float* __restrict__ out) {
    const int blk  = blockIdx.x;
    const int c    = blk & (NCHUNK - 1);
    const int bm   = blk >> 3;
    const int m    = bm & (MH - 1);
    const int b    = bm >> 2;

    const int tid  = threadIdx.x;
    const int w    = tid >> 6;
    const int lane = tid & 63;

    const int bP = b * SEQ;
    const int p0 = c * CHUNK;

    __shared__ float lds_red[WAVES];
    __shared__ float lds_Sb[WAVES];
    __shared__ float lds_Sc[WAVES];
    __shared__ float lds_Ab[WAVES][DIM];
    __shared__ float lds_Ac[WAVES][DIM];

    // ---- phase A: G = max(pre) over [0, p0+CHUNK) for this (b,m) chain ----
    const int npos = p0 + CHUNK;
    float gmax = -INFINITY;
    for (int p = tid; p < npos; p += THREADS)
        gmax = fmaxf(gmax, pre[(size_t)(bP + p) * MH + m]);
    #pragma unroll
    for (int off = 32; off > 0; off >>= 1)
        gmax = fmaxf(gmax, __shfl_xor(gmax, off, 64));
    if (lane == 0) lds_red[w] = gmax;
    __syncthreads();
    float G = lds_red[0];
    #pragma unroll
    for (int j = 1; j < WAVES; ++j) G = fmaxf(G, lds_red[j]);

    // ---- phase B: partial sums over previous chunks [0, p0) ----
    // groups of 16 positions; wave w takes groups g = w, w+8, ..., covering all.
    float Sb0 = 0.f, Sb1 = 0.f, Ab0 = 0.f, Ab1 = 0.f;
    for (int t = 0; t < c; ++t) {
        const int g  = w + t * 8;
        const int q0 = g * 16;
        float pre_b = (lane < 16) ? pre[(size_t)(bP + q0 + lane) * MH + m] : 0.f;
        const float* vb = values + (size_t)(bP + q0) * DIM + lane;
        #pragma unroll
        for (int i = 0; i < 16; i += 2) {
            float w0 = __expf(__shfl(pre_b, i, 64) - G);
            float w1 = __expf(__shfl(pre_b, i + 1, 64) - G);
            Sb0 += w0;
            Sb1 += w1;
            Ab0 = fmaf(w0, vb[(size_t)i * DIM], Ab0);
            Ab1 = fmaf(w1, vb[(size_t)(i + 1) * DIM], Ab1);
        }
    }
    if (lane == 0) lds_Sb[w] = Sb0 + Sb1;
    lds_Ab[w][lane] = Ab0 + Ab1;

    // ---- phase C pass 1: this wave's 16-position local sums ----
    const int q0c = p0 + w * WSEG;
    float pre_c  = (lane < 16) ? pre[(size_t)(bP + q0c + lane) * MH + m] : 0.f;
    float mask_c = (lane < 16) ? mask[bP + q0c + lane] : 0.f;
    const float* vc = values + (size_t)(bP + q0c) * DIM + lane;
    float Sc = 0.f, Ac = 0.f;
    #pragma unroll
    for (int i = 0; i < WSEG; ++i) {
        float wq = __expf(__shfl(pre_c, i, 64) - G);
        Sc += wq;
        Ac = fmaf(wq, vc[(size_t)i * DIM], Ac);
    }
    if (lane == 0) lds_Sc[w] = Sc;
    lds_Ac[w][lane] = Ac;
    __syncthreads();

    // ---- prefix for this wave: all phase-B partials + earlier waves' locals ----
    float S = 0.f, A = 0.f;
    #pragma unroll
    for (int j = 0; j < WAVES; ++j) { S += lds_Sb[j]; A += lds_Ab[j][lane]; }
    for (int j = 0; j < w; ++j)     { S += lds_Sc[j]; A += lds_Ac[j][lane]; }

    // ---- phase C pass 2: rescan 16 positions, write out ----
    float* op = out + ((size_t)(bP + q0c) * MH + m) * DIM + lane;
    #pragma unroll
    for (int i = 0; i < WSEG; ++i) {
        float wq = __expf(__shfl(pre_c, i, 64) - G);
        float vv = vc[(size_t)i * DIM];
        S += wq;
        A = fmaf(wq, vv, A);
        float mk = __shfl(mask_c, i, 64);
        op[(size_t)i * MH * DIM] = A * (mk * __builtin_amdgcn_rcpf(S));
    }
}

extern "C" void kernel_launch(void* const* d_in, const int* in_sizes, int n_in,
                              void* d_out, int out_size, void* d_ws, size_t ws_size,
                              hipStream_t stream) {
    const float* values = (const float*)d_in[0];
    const float* pre    = (const float*)d_in[1];
    const float* mask   = (const float*)d_in[2];
    float*       out    = (float*)d_out;

    dim3 grid(BATCH * MH * NCHUNK);   // 512 blocks
    dim3 block(THREADS);              // 512 threads = 8 waves
    hipLaunchKernelGGL(teedam_kernel, grid, block, 0, stream,
                       values, pre, mask, out);
}